// Round 2
// baseline (834.723 us; speedup 1.0000x reference)
//
#include <hip/hip_runtime.h>

#define Bsz 256
#define Ssz 512
#define Esz 100
#define Hsz 64
#define Gsz 256                       // 4*H
#define Kp  128                       // K padded to MFMA multiple
#define SBG (512u * 256u * 256u)      // S*B*G per direction

using short8 = __attribute__((ext_vector_type(8))) short;   // 8 bf16 (4 VGPRs)
using f32x4  = __attribute__((ext_vector_type(4))) float;   // MFMA accumulator

__device__ __forceinline__ float sigf(float x) { return 1.0f / (1.0f + __expf(-x)); }
__device__ __forceinline__ float tanhfast(float x) { return 2.0f / (1.0f + __expf(-2.0f * x)) - 1.0f; }

__device__ __forceinline__ unsigned short f2bf(float f) {
    unsigned int u = __float_as_uint(f);
    unsigned int rnd = 0x7fffu + ((u >> 16) & 1u);   // RNE
    return (unsigned short)((u + rnd) >> 16);
}
__device__ __forceinline__ float bf2f(unsigned short us) {
    return __uint_as_float(((unsigned int)us) << 16);
}

// ============================================================
// Pre-convert: emb -> bf16 padded [50000][128]; W_ih -> bf16 padded [2][256][128]
// ============================================================
__global__ void conv_emb(const float* __restrict__ emb, unsigned short* __restrict__ embp) {
    int idx = blockIdx.x * 256 + threadIdx.x;   // 50000*128 = 6,400,000
    if (idx >= 50000 * Kp) return;
    int row = idx >> 7, c = idx & 127;
    float v = (c < Esz) ? emb[row * Esz + c] : 0.f;
    embp[idx] = f2bf(v);
}
__global__ void conv_w(const float* __restrict__ Wf, const float* __restrict__ Wb,
                       unsigned short* __restrict__ Wp) {
    int idx = blockIdx.x * 256 + threadIdx.x;   // 2*256*128 = 65536
    int d = idx >> 15, r = (idx >> 7) & 255, c = idx & 127;
    const float* W = d ? Wb : Wf;
    float v = (c < Esz) ? W[r * Esz + c] : 0.f;
    Wp[idx] = f2bf(v);
}

// ============================================================
// Kernel 1: MFMA pregate GEMM. Tile 128(M) x 128(N), K=128 (one staging).
// 512 thr = 8 waves (2M x 4N), wave tile 64x32 -> 4x2 frags of 16x16x32.
// A rows = gathered embp rows (m = s*256+b); B rows = W rows ([N][K] = B^T).
// Both LDS tiles XOR-swizzled: byte ^= (row&7)<<4 -> conflict-free b128 frags.
// ============================================================
__global__ __launch_bounds__(512) void pregate_mfma(
    const int* __restrict__ x, const unsigned short* __restrict__ embp,
    const unsigned short* __restrict__ Wp,
    const float* __restrict__ bihf, const float* __restrict__ bhhf,
    const float* __restrict__ bihb, const float* __restrict__ bhhb,
    unsigned short* __restrict__ preg)
{
    __shared__ unsigned short As[128 * Kp];   // 32 KB
    __shared__ unsigned short Bs[128 * Kp];   // 32 KB

    const int t   = threadIdx.x;
    const int mb  = blockIdx.x;   // 1024
    const int nb  = blockIdx.y;   // 2
    const int dir = blockIdx.z;   // 2

    // ---- stage A: 128 rows x 16 chunks(16B) ----
    #pragma unroll
    for (int it = 0; it < 4; ++it) {
        int i = t + it * 512;
        int row = i >> 4, c = i & 15;
        int m = mb * 128 + row;
        int s = m >> 8, b = m & 255;
        int xv = x[b * Ssz + s];
        uint4 v = *(const uint4*)(embp + (size_t)xv * Kp + c * 8);
        int dst = ((row << 8) + (c << 4)) ^ ((row & 7) << 4);
        *(uint4*)((char*)As + dst) = v;
    }
    // ---- stage B: 128 gate-rows x 16 chunks ----
    const unsigned short* Wd = Wp + ((size_t)dir * Gsz + (size_t)nb * 128) * Kp;
    #pragma unroll
    for (int it = 0; it < 4; ++it) {
        int i = t + it * 512;
        int g = i >> 4, c = i & 15;
        uint4 v = *(const uint4*)(Wd + g * Kp + c * 8);
        int dst = ((g << 8) + (c << 4)) ^ ((g & 7) << 4);
        *(uint4*)((char*)Bs + dst) = v;
    }
    __syncthreads();

    const int w  = t >> 6, l = t & 63;
    const int wm = w >> 2, wn = w & 3;      // 2 x 4 waves
    const int lr = l & 15, lk = l >> 4;     // fragment row/col, k-group

    f32x4 acc[4][2];
    #pragma unroll
    for (int mi = 0; mi < 4; ++mi)
        #pragma unroll
        for (int ni = 0; ni < 2; ++ni)
            acc[mi][ni] = (f32x4){0.f, 0.f, 0.f, 0.f};

    #pragma unroll
    for (int ks = 0; ks < 4; ++ks) {
        short8 a[4], bf[2];
        #pragma unroll
        for (int mi = 0; mi < 4; ++mi) {
            int row = wm * 64 + mi * 16 + lr;
            int off = ((row << 8) + (ks << 6) + (lk << 4)) ^ ((row & 7) << 4);
            a[mi] = *(const short8*)((const char*)As + off);
        }
        #pragma unroll
        for (int ni = 0; ni < 2; ++ni) {
            int g = wn * 32 + ni * 16 + lr;
            int off = ((g << 8) + (ks << 6) + (lk << 4)) ^ ((g & 7) << 4);
            bf[ni] = *(const short8*)((const char*)Bs + off);
        }
        #pragma unroll
        for (int mi = 0; mi < 4; ++mi)
            #pragma unroll
            for (int ni = 0; ni < 2; ++ni)
                acc[mi][ni] = __builtin_amdgcn_mfma_f32_16x16x32_bf16(a[mi], bf[ni], acc[mi][ni], 0, 0, 0);
    }

    // ---- epilogue: +bias, bf16 store. C/D: col=lane&15, row=(lane>>4)*4+j ----
    const float* bih = dir ? bihb : bihf;
    const float* bhh = dir ? bhhb : bhhf;
    unsigned short* pd = preg + (size_t)dir * SBG;
    #pragma unroll
    for (int ni = 0; ni < 2; ++ni) {
        int g = nb * 128 + wn * 32 + ni * 16 + lr;
        float bias = bih[g] + bhh[g];
        #pragma unroll
        for (int mi = 0; mi < 4; ++mi) {
            #pragma unroll
            for (int j = 0; j < 4; ++j) {
                int m = mb * 128 + wm * 64 + mi * 16 + lk * 4 + j;
                pd[(size_t)m * Gsz + g] = f2bf(acc[mi][ni][j] + bias);
            }
        }
    }
}

// ============================================================
// Kernel 2: LSTM recurrence — ONE WAVE per (sample, dir) chain, no barriers.
// Lane k owns hidden unit k: W_hh rows i,f,g,o in 256 VGPRs. h broadcast via
// wave-synchronous LDS. 512 blocks x 64 threads.
// ============================================================
__global__ __launch_bounds__(64, 1) void lstm_rec(
    const unsigned short* __restrict__ preg,
    const float* __restrict__ Whhf, const float* __restrict__ Whhb,
    float* __restrict__ hfinal)
{
    __shared__ __align__(16) float h_s[Hsz];

    const int k   = threadIdx.x;
    const int b   = blockIdx.x & 255;
    const int dir = blockIdx.x >> 8;
    const float* __restrict__ Whh = dir ? Whhb : Whhf;

    float4 wi[16], wf[16], wg[16], wo[16];   // 256 VGPRs of weights
    #pragma unroll
    for (int j = 0; j < 16; ++j) {
        wi[j] = *(const float4*)&Whh[(0 * Hsz + k) * Hsz + 4 * j];
        wf[j] = *(const float4*)&Whh[(1 * Hsz + k) * Hsz + 4 * j];
        wg[j] = *(const float4*)&Whh[(2 * Hsz + k) * Hsz + 4 * j];
        wo[j] = *(const float4*)&Whh[(3 * Hsz + k) * Hsz + 4 * j];
    }

    const unsigned short* __restrict__ pd = preg + (size_t)dir * SBG;
    h_s[k] = 0.f;
    float c_ = 0.f, hlast = 0.f;
    __syncthreads();

    const int s0 = dir ? (Ssz - 1) : 0;
    size_t base = ((size_t)s0 * Bsz + b) * Gsz;
    float pgi = bf2f(pd[base + k]);
    float pgf = bf2f(pd[base + 64 + k]);
    float pgg = bf2f(pd[base + 128 + k]);
    float pgo = bf2f(pd[base + 192 + k]);

    for (int s = 0; s < Ssz; ++s) {
        // prefetch next step's 4 pregates (clamped; unused on last iter)
        int sn = (s + 1 < Ssz) ? s + 1 : s;
        int se = dir ? (Ssz - 1 - sn) : sn;
        size_t nbase = ((size_t)se * Bsz + b) * Gsz;
        float ni_ = bf2f(pd[nbase + k]);
        float nf_ = bf2f(pd[nbase + 64 + k]);
        float ng_ = bf2f(pd[nbase + 128 + k]);
        float no_ = bf2f(pd[nbase + 192 + k]);

        // 4 gates for unit k: 4 independent 64-FMA chains over broadcast h
        float ai = pgi, af = pgf, ag = pgg, ao = pgo;
        #pragma unroll
        for (int j = 0; j < 16; ++j) {
            float4 hv = *(const float4*)&h_s[4 * j];
            ai = fmaf(hv.x, wi[j].x, ai); ai = fmaf(hv.y, wi[j].y, ai);
            ai = fmaf(hv.z, wi[j].z, ai); ai = fmaf(hv.w, wi[j].w, ai);
            af = fmaf(hv.x, wf[j].x, af); af = fmaf(hv.y, wf[j].y, af);
            af = fmaf(hv.z, wf[j].z, af); af = fmaf(hv.w, wf[j].w, af);
            ag = fmaf(hv.x, wg[j].x, ag); ag = fmaf(hv.y, wg[j].y, ag);
            ag = fmaf(hv.z, wg[j].z, ag); ag = fmaf(hv.w, wg[j].w, ag);
            ao = fmaf(hv.x, wo[j].x, ao); ao = fmaf(hv.y, wo[j].y, ao);
            ao = fmaf(hv.z, wo[j].z, ao); ao = fmaf(hv.w, wo[j].w, ao);
        }

        float gi = sigf(ai), gf = sigf(af), gg_ = tanhfast(ag), go = sigf(ao);
        c_    = fmaf(gf, c_, gi * gg_);
        hlast = go * tanhfast(c_);

        h_s[k] = hlast;
        __syncthreads();   // single-wave block: compiles to lgkm wait (+elided barrier)
        pgi = ni_; pgf = nf_; pgg = ng_; pgo = no_;
    }
    hfinal[((size_t)dir * Bsz + b) * Hsz + k] = hlast;
}

// ============================================================
// Kernel 3: out[b] = sigmoid([h_f, h_b] . fc_w + fc_b)
// ============================================================
__global__ void fc_head(const float* __restrict__ hf,
                        const float* __restrict__ fcw, const float* __restrict__ fcb,
                        float* __restrict__ out)
{
    const int b = threadIdx.x;
    float sum = fcb[0];
    const float* h1 = hf + b * Hsz;
    const float* h2 = hf + Bsz * Hsz + b * Hsz;
    #pragma unroll 8
    for (int j = 0; j < Hsz; ++j) sum = fmaf(h1[j], fcw[j], sum);
    #pragma unroll 8
    for (int j = 0; j < Hsz; ++j) sum = fmaf(h2[j], fcw[Hsz + j], sum);
    out[b] = 1.0f / (1.0f + __expf(-sum));
}

extern "C" void kernel_launch(void* const* d_in, const int* in_sizes, int n_in,
                              void* d_out, int out_size, void* d_ws, size_t ws_size,
                              hipStream_t stream)
{
    const int*   x    = (const int*)d_in[0];
    const float* emb  = (const float*)d_in[1];
    const float* Wihf = (const float*)d_in[2];
    const float* Whhf = (const float*)d_in[3];
    const float* bihf = (const float*)d_in[4];
    const float* bhhf = (const float*)d_in[5];
    const float* Wihb = (const float*)d_in[6];
    const float* Whhb = (const float*)d_in[7];
    const float* bihb = (const float*)d_in[8];
    const float* bhhb = (const float*)d_in[9];
    const float* fcw  = (const float*)d_in[10];
    const float* fcb  = (const float*)d_in[11];

    // ws layout (bytes):
    //   [0, 134217728)              preg   2 x S*B*G bf16
    //   [134217728, 134348800)      hf     2*B*H f32
    //   [134348800, 147148800)      embp   50000*128 bf16 (padded)
    //   [147148800, 147279872)      Wp     2*256*128 bf16 (padded)
    unsigned short* preg = (unsigned short*)d_ws;
    float*          hf   = (float*)((char*)d_ws + 134217728u);
    unsigned short* embp = (unsigned short*)((char*)d_ws + 134348800u);
    unsigned short* Wp   = (unsigned short*)((char*)d_ws + 147148800u);

    conv_emb<<<25000, 256, 0, stream>>>(emb, embp);
    conv_w<<<256, 256, 0, stream>>>(Wihf, Wihb, Wp);
    pregate_mfma<<<dim3(1024, 2, 2), 512, 0, stream>>>(x, embp, Wp,
                                                       bihf, bhhf, bihb, bhhb, preg);
    lstm_rec<<<512, 64, 0, stream>>>(preg, Whhf, Whhb, hf);
    fc_head<<<1, 256, 0, stream>>>(hf, fcw, fcb, (float*)d_out);
}

// Round 3
// 711.499 us; speedup vs baseline: 1.1732x; 1.1732x over previous
//
#include <hip/hip_runtime.h>

#define Bsz 256
#define Ssz 512
#define Esz 100
#define Hsz 64
#define Gsz 256                       // 4*H
#define Kp  128                       // K padded to MFMA multiple
#define SBG (512u * 256u * 256u)      // S*B*G per direction

using short8 = __attribute__((ext_vector_type(8))) short;   // 8 bf16 (4 VGPRs)
using f32x4  = __attribute__((ext_vector_type(4))) float;   // MFMA accumulator
using f32x2  = __attribute__((ext_vector_type(2))) float;   // pk_fma candidate

__device__ __forceinline__ float sigf(float x) { return 1.0f / (1.0f + __expf(-x)); }
__device__ __forceinline__ float tanhfast(float x) { return 2.0f / (1.0f + __expf(-2.0f * x)) - 1.0f; }

__device__ __forceinline__ unsigned short f2bf(float f) {
    unsigned int u = __float_as_uint(f);
    unsigned int rnd = 0x7fffu + ((u >> 16) & 1u);   // RNE
    return (unsigned short)((u + rnd) >> 16);
}
__device__ __forceinline__ float bf2f(unsigned short us) {
    return __uint_as_float(((unsigned int)us) << 16);
}
__device__ __forceinline__ float lane_bcast(float v, int lane) {
    return __uint_as_float((unsigned int)__builtin_amdgcn_readlane((int)__float_as_uint(v), lane));
}

// ============================================================
// Pre-convert: emb -> bf16 padded [50000][128]; W_ih -> bf16 padded [2][256][128]
// ============================================================
__global__ void conv_emb(const float* __restrict__ emb, unsigned short* __restrict__ embp) {
    int idx = blockIdx.x * 256 + threadIdx.x;
    if (idx >= 50000 * Kp) return;
    int row = idx >> 7, c = idx & 127;
    float v = (c < Esz) ? emb[row * Esz + c] : 0.f;
    embp[idx] = f2bf(v);
}
__global__ void conv_w(const float* __restrict__ Wf, const float* __restrict__ Wb,
                       unsigned short* __restrict__ Wp) {
    int idx = blockIdx.x * 256 + threadIdx.x;
    int d = idx >> 15, r = (idx >> 7) & 255, c = idx & 127;
    const float* W = d ? Wb : Wf;
    float v = (c < Esz) ? W[r * Esz + c] : 0.f;
    Wp[idx] = f2bf(v);
}

// ============================================================
// Kernel 1: MFMA pregate GEMM (unchanged structure from R2, passed).
// Epilogue now stores gate-permuted: row pos = unit*4 + gate_type, so the
// recurrence can load (i,f,g,o) of unit k as one ushort4.
// ============================================================
__global__ __launch_bounds__(512) void pregate_mfma(
    const int* __restrict__ x, const unsigned short* __restrict__ embp,
    const unsigned short* __restrict__ Wp,
    const float* __restrict__ bihf, const float* __restrict__ bhhf,
    const float* __restrict__ bihb, const float* __restrict__ bhhb,
    unsigned short* __restrict__ preg)
{
    __shared__ unsigned short As[128 * Kp];   // 32 KB
    __shared__ unsigned short Bs[128 * Kp];   // 32 KB

    const int t   = threadIdx.x;
    const int mb  = blockIdx.x;   // 1024
    const int nb  = blockIdx.y;   // 2
    const int dir = blockIdx.z;   // 2

    #pragma unroll
    for (int it = 0; it < 4; ++it) {
        int i = t + it * 512;
        int row = i >> 4, c = i & 15;
        int m = mb * 128 + row;
        int s = m >> 8, b = m & 255;
        int xv = x[b * Ssz + s];
        uint4 v = *(const uint4*)(embp + (size_t)xv * Kp + c * 8);
        int dst = ((row << 8) + (c << 4)) ^ ((row & 7) << 4);
        *(uint4*)((char*)As + dst) = v;
    }
    const unsigned short* Wd = Wp + ((size_t)dir * Gsz + (size_t)nb * 128) * Kp;
    #pragma unroll
    for (int it = 0; it < 4; ++it) {
        int i = t + it * 512;
        int g = i >> 4, c = i & 15;
        uint4 v = *(const uint4*)(Wd + g * Kp + c * 8);
        int dst = ((g << 8) + (c << 4)) ^ ((g & 7) << 4);
        *(uint4*)((char*)Bs + dst) = v;
    }
    __syncthreads();

    const int w  = t >> 6, l = t & 63;
    const int wm = w >> 2, wn = w & 3;
    const int lr = l & 15, lk = l >> 4;

    f32x4 acc[4][2];
    #pragma unroll
    for (int mi = 0; mi < 4; ++mi)
        #pragma unroll
        for (int ni = 0; ni < 2; ++ni)
            acc[mi][ni] = (f32x4){0.f, 0.f, 0.f, 0.f};

    #pragma unroll
    for (int ks = 0; ks < 4; ++ks) {
        short8 a[4], bf[2];
        #pragma unroll
        for (int mi = 0; mi < 4; ++mi) {
            int row = wm * 64 + mi * 16 + lr;
            int off = ((row << 8) + (ks << 6) + (lk << 4)) ^ ((row & 7) << 4);
            a[mi] = *(const short8*)((const char*)As + off);
        }
        #pragma unroll
        for (int ni = 0; ni < 2; ++ni) {
            int g = wn * 32 + ni * 16 + lr;
            int off = ((g << 8) + (ks << 6) + (lk << 4)) ^ ((g & 7) << 4);
            bf[ni] = *(const short8*)((const char*)Bs + off);
        }
        #pragma unroll
        for (int mi = 0; mi < 4; ++mi)
            #pragma unroll
            for (int ni = 0; ni < 2; ++ni)
                acc[mi][ni] = __builtin_amdgcn_mfma_f32_16x16x32_bf16(a[mi], bf[ni], acc[mi][ni], 0, 0, 0);
    }

    const float* bih = dir ? bihb : bihf;
    const float* bhh = dir ? bhhb : bhhf;
    unsigned short* pd = preg + (size_t)dir * SBG;
    #pragma unroll
    for (int ni = 0; ni < 2; ++ni) {
        int g = nb * 128 + wn * 32 + ni * 16 + lr;        // global gate idx
        int gpos = ((g & 63) << 2) | (g >> 6);            // unit-major permuted pos
        float bias = bih[g] + bhh[g];
        #pragma unroll
        for (int mi = 0; mi < 4; ++mi) {
            #pragma unroll
            for (int j = 0; j < 4; ++j) {
                int m = mb * 128 + wm * 64 + mi * 16 + lk * 4 + j;
                pd[(size_t)m * Gsz + gpos] = f2bf(acc[mi][ni][j] + bias);
            }
        }
    }
}

// ============================================================
// Kernel 2: LSTM recurrence — one wave per (sample,dir), ZERO barriers,
// ZERO LDS. h broadcast via v_readlane (pure VALU). Pregates prefetched
// 2 steps ahead (one ushort4 = i,f,g,o of unit k). float2 chains invite
// v_pk_fma_f32.
// ============================================================
__global__ __launch_bounds__(64, 1) void lstm_rec(
    const unsigned short* __restrict__ preg,
    const float* __restrict__ Whhf, const float* __restrict__ Whhb,
    float* __restrict__ hfinal)
{
    const int k   = threadIdx.x;     // hidden unit (lane)
    const int b   = blockIdx.x & 255;
    const int dir = blockIdx.x >> 8;
    const float* __restrict__ Whh = dir ? Whhb : Whhf;

    // W_hh rows i,f,g,o for unit k: 256 VGPRs as f32x2
    f32x2 w2i[32], w2f[32], w2g[32], w2o[32];
    #pragma unroll
    for (int j = 0; j < 32; ++j) {
        w2i[j] = *(const f32x2*)&Whh[(0 * Hsz + k) * Hsz + 2 * j];
        w2f[j] = *(const f32x2*)&Whh[(1 * Hsz + k) * Hsz + 2 * j];
        w2g[j] = *(const f32x2*)&Whh[(2 * Hsz + k) * Hsz + 2 * j];
        w2o[j] = *(const f32x2*)&Whh[(3 * Hsz + k) * Hsz + 2 * j];
    }

    // pregate walk: elem offset dir*SBG + (s_eff*Bsz + b)*Gsz + 4k, s_eff step
    const ptrdiff_t sb = (dir ? -1 : 1) * (ptrdiff_t)(Bsz * Gsz) * 2;  // bytes/step
    const char* pbase = (const char*)preg +
        ((size_t)dir * SBG + ((size_t)(dir ? Ssz - 1 : 0) * Bsz + b) * Gsz + 4 * k) * 2;

    ushort4 pgA = *(const ushort4*)(pbase);            // step 0
    ushort4 pgB = *(const ushort4*)(pbase + sb);       // step 1
    const char* pc = pbase + 2 * sb;                   // prefetch cursor (step 2)

    float c_ = 0.f, h_k = 0.f;

    #define LSTM_STEP(PG, PGN)                                            \
    {                                                                     \
        ushort4 nxt = *(const ushort4*)(pc); pc += sb;                    \
        f32x2 Ai = {bf2f(PG.x), 0.f}, Af = {bf2f(PG.y), 0.f};             \
        f32x2 Ag = {bf2f(PG.z), 0.f}, Ao = {bf2f(PG.w), 0.f};             \
        _Pragma("unroll")                                                 \
        for (int j = 0; j < 32; ++j) {                                    \
            f32x2 h2 = {lane_bcast(h_k, 2 * j), lane_bcast(h_k, 2 * j + 1)}; \
            Ai += h2 * w2i[j];                                            \
            Af += h2 * w2f[j];                                            \
            Ag += h2 * w2g[j];                                            \
            Ao += h2 * w2o[j];                                            \
        }                                                                 \
        float gi = sigf(Ai.x + Ai.y);                                     \
        float gf = sigf(Af.x + Af.y);                                     \
        float gG = tanhfast(Ag.x + Ag.y);                                 \
        float go = sigf(Ao.x + Ao.y);                                     \
        c_  = fmaf(gf, c_, gi * gG);                                      \
        h_k = go * tanhfast(c_);                                          \
        PGN = nxt;                                                        \
    }

    for (int s = 0; s < Ssz; s += 2) {
        LSTM_STEP(pgA, pgA);       // compute step s, prefetch s+2
        LSTM_STEP(pgB, pgB);       // compute step s+1, prefetch s+3
    }
    #undef LSTM_STEP

    hfinal[((size_t)dir * Bsz + b) * Hsz + k] = h_k;
}

// ============================================================
// Kernel 3: out[b] = sigmoid([h_f, h_b] . fc_w + fc_b)
// ============================================================
__global__ void fc_head(const float* __restrict__ hf,
                        const float* __restrict__ fcw, const float* __restrict__ fcb,
                        float* __restrict__ out)
{
    const int b = threadIdx.x;
    float sum = fcb[0];
    const float* h1 = hf + b * Hsz;
    const float* h2 = hf + Bsz * Hsz + b * Hsz;
    #pragma unroll 8
    for (int j = 0; j < Hsz; ++j) sum = fmaf(h1[j], fcw[j], sum);
    #pragma unroll 8
    for (int j = 0; j < Hsz; ++j) sum = fmaf(h2[j], fcw[Hsz + j], sum);
    out[b] = 1.0f / (1.0f + __expf(-sum));
}

extern "C" void kernel_launch(void* const* d_in, const int* in_sizes, int n_in,
                              void* d_out, int out_size, void* d_ws, size_t ws_size,
                              hipStream_t stream)
{
    const int*   x    = (const int*)d_in[0];
    const float* emb  = (const float*)d_in[1];
    const float* Wihf = (const float*)d_in[2];
    const float* Whhf = (const float*)d_in[3];
    const float* bihf = (const float*)d_in[4];
    const float* bhhf = (const float*)d_in[5];
    const float* Wihb = (const float*)d_in[6];
    const float* Whhb = (const float*)d_in[7];
    const float* bihb = (const float*)d_in[8];
    const float* bhhb = (const float*)d_in[9];
    const float* fcw  = (const float*)d_in[10];
    const float* fcb  = (const float*)d_in[11];

    // ws layout (bytes):
    //   [0, 134217728)              preg   2 x S*B*G bf16 (unit-major gates)
    //   [134217728, 134348800)      hf     2*B*H f32
    //   [134348800, 147148800)      embp   50000*128 bf16 (padded)
    //   [147148800, 147279872)      Wp     2*256*128 bf16 (padded)
    unsigned short* preg = (unsigned short*)d_ws;
    float*          hf   = (float*)((char*)d_ws + 134217728u);
    unsigned short* embp = (unsigned short*)((char*)d_ws + 134348800u);
    unsigned short* Wp   = (unsigned short*)((char*)d_ws + 147148800u);

    conv_emb<<<25000, 256, 0, stream>>>(emb, embp);
    conv_w<<<256, 256, 0, stream>>>(Wihf, Wihb, Wp);
    pregate_mfma<<<dim3(1024, 2, 2), 512, 0, stream>>>(x, embp, Wp,
                                                       bihf, bhhf, bihb, bhhb, preg);
    lstm_rec<<<512, 64, 0, stream>>>(preg, Whhf, Whhb, hf);
    fc_head<<<1, 256, 0, stream>>>(hf, fcw, fcb, (float*)d_out);
}

// Round 4
// 382.190 us; speedup vs baseline: 2.1841x; 1.8616x over previous
//
#include <hip/hip_runtime.h>

#define Bsz 256
#define Ssz 512
#define Esz 100
#define Hsz 64
#define Gsz 256                       // 4*H
#define Kp  128                       // K padded to MFMA multiple
#define Vsz 50000
#define Vpad 50048                    // 391 * 128

using short8 = __attribute__((ext_vector_type(8))) short;   // 8 bf16 (4 VGPRs)
using f32x4  = __attribute__((ext_vector_type(4))) float;   // MFMA accumulator
using h2     = __attribute__((ext_vector_type(2))) _Float16;

// fast activations: v_exp_f32 (2^x) + v_rcp_f32
#define LOG2E 1.4426950408889634f
__device__ __forceinline__ float sigf(float x) {
    return __builtin_amdgcn_rcpf(1.0f + __builtin_amdgcn_exp2f(-LOG2E * x));
}
__device__ __forceinline__ float tanhfast(float x) {
    return 2.0f * __builtin_amdgcn_rcpf(1.0f + __builtin_amdgcn_exp2f(-2.0f * LOG2E * x)) - 1.0f;
}

__device__ __forceinline__ unsigned short f2bf(float f) {
    unsigned int u = __float_as_uint(f);
    unsigned int rnd = 0x7fffu + ((u >> 16) & 1u);   // RNE
    return (unsigned short)((u + rnd) >> 16);
}
__device__ __forceinline__ unsigned short f2h(float f) {
    return __builtin_bit_cast(unsigned short, (_Float16)f);
}
__device__ __forceinline__ unsigned int pack2f16(float a, float b) {
    return (unsigned int)f2h(a) | ((unsigned int)f2h(b) << 16);
}

// ============================================================
// Pre-convert: emb -> bf16 padded [50000][128]; W_ih -> bf16 padded [2][256][128]
// ============================================================
__global__ void conv_emb(const float* __restrict__ emb, unsigned short* __restrict__ embp) {
    int idx = blockIdx.x * 256 + threadIdx.x;
    if (idx >= Vsz * Kp) return;
    int row = idx >> 7, c = idx & 127;
    float v = (c < Esz) ? emb[row * Esz + c] : 0.f;
    embp[idx] = f2bf(v);
}
__global__ void conv_w(const float* __restrict__ Wf, const float* __restrict__ Wb,
                       unsigned short* __restrict__ Wp) {
    int idx = blockIdx.x * 256 + threadIdx.x;
    int d = idx >> 15, r = (idx >> 7) & 255, c = idx & 127;
    const float* W = d ? Wb : Wf;
    float v = (c < Esz) ? W[r * Esz + c] : 0.f;
    Wp[idx] = f2bf(v);
}

// ============================================================
// Kernel 1: vocab pregate table. tbl[dir][v][gpos] (f16, unit-major) =
// emb[v] @ W_ih.T + (b_ih + b_hh). M = vocab (50048 padded), N = 256, K = 128.
// Same verified MFMA tile structure as R2/R3, minus the x-gather.
// ============================================================
__global__ __launch_bounds__(512) void pregate_mfma(
    const unsigned short* __restrict__ embp,
    const unsigned short* __restrict__ Wp,
    const float* __restrict__ bihf, const float* __restrict__ bhhf,
    const float* __restrict__ bihb, const float* __restrict__ bhhb,
    unsigned short* __restrict__ tbl)
{
    __shared__ unsigned short As[128 * Kp];   // 32 KB
    __shared__ unsigned short Bs[128 * Kp];   // 32 KB

    const int t   = threadIdx.x;
    const int mb  = blockIdx.x;   // 391 vocab tiles
    const int nb  = blockIdx.y;   // 2
    const int dir = blockIdx.z;   // 2

    #pragma unroll
    for (int it = 0; it < 4; ++it) {
        int i = t + it * 512;
        int row = i >> 4, c = i & 15;
        int vr = mb * 128 + row; if (vr > Vsz - 1) vr = Vsz - 1;
        uint4 v = *(const uint4*)(embp + (size_t)vr * Kp + c * 8);
        int dst = ((row << 8) + (c << 4)) ^ ((row & 7) << 4);
        *(uint4*)((char*)As + dst) = v;
    }
    const unsigned short* Wd = Wp + ((size_t)dir * Gsz + (size_t)nb * 128) * Kp;
    #pragma unroll
    for (int it = 0; it < 4; ++it) {
        int i = t + it * 512;
        int g = i >> 4, c = i & 15;
        uint4 v = *(const uint4*)(Wd + g * Kp + c * 8);
        int dst = ((g << 8) + (c << 4)) ^ ((g & 7) << 4);
        *(uint4*)((char*)Bs + dst) = v;
    }
    __syncthreads();

    const int w  = t >> 6, l = t & 63;
    const int wm = w >> 2, wn = w & 3;
    const int lr = l & 15, lk = l >> 4;

    f32x4 acc[4][2];
    #pragma unroll
    for (int mi = 0; mi < 4; ++mi)
        #pragma unroll
        for (int ni = 0; ni < 2; ++ni)
            acc[mi][ni] = (f32x4){0.f, 0.f, 0.f, 0.f};

    #pragma unroll
    for (int ks = 0; ks < 4; ++ks) {
        short8 a[4], bf[2];
        #pragma unroll
        for (int mi = 0; mi < 4; ++mi) {
            int row = wm * 64 + mi * 16 + lr;
            int off = ((row << 8) + (ks << 6) + (lk << 4)) ^ ((row & 7) << 4);
            a[mi] = *(const short8*)((const char*)As + off);
        }
        #pragma unroll
        for (int ni = 0; ni < 2; ++ni) {
            int g = wn * 32 + ni * 16 + lr;
            int off = ((g << 8) + (ks << 6) + (lk << 4)) ^ ((g & 7) << 4);
            bf[ni] = *(const short8*)((const char*)Bs + off);
        }
        #pragma unroll
        for (int mi = 0; mi < 4; ++mi)
            #pragma unroll
            for (int ni = 0; ni < 2; ++ni)
                acc[mi][ni] = __builtin_amdgcn_mfma_f32_16x16x32_bf16(a[mi], bf[ni], acc[mi][ni], 0, 0, 0);
    }

    // epilogue: +bias, f16 store, unit-major gpos = (g&63)*4 + (g>>6)
    const float* bih = dir ? bihb : bihf;
    const float* bhh = dir ? bhhb : bhhf;
    unsigned short* td = tbl + (size_t)dir * Vpad * Gsz;
    #pragma unroll
    for (int ni = 0; ni < 2; ++ni) {
        int g = nb * 128 + wn * 32 + ni * 16 + lr;
        int gpos = ((g & 63) << 2) | (g >> 6);
        float bias = bih[g] + bhh[g];
        #pragma unroll
        for (int mi = 0; mi < 4; ++mi) {
            #pragma unroll
            for (int j = 0; j < 4; ++j) {
                int vrow = mb * 128 + wm * 64 + mi * 16 + lk * 4 + j;   // < 50048
                td[(size_t)vrow * Gsz + gpos] = f2h(acc[mi][ni][j] + bias);
            }
        }
    }
}

// ============================================================
// Kernel 2: LSTM recurrence — one wave per (sample,dir). W_hh as packed
// f16 pairs (128 VGPRs, no spill); 128 x v_dot2_f32_f16 per step; h
// broadcast as packed f16 via shfl_xor-pack + 32 readlanes. Pregate rows
// gathered from the L3-resident vocab table, 2 steps ahead; token ids
// (scalar loads) 4 steps ahead.
// ============================================================
__global__ __launch_bounds__(64, 1) void lstm_rec(
    const int* __restrict__ x,
    const unsigned short* __restrict__ tbl,
    const float* __restrict__ Whhf, const float* __restrict__ Whhb,
    float* __restrict__ hfinal)
{
    const int k   = threadIdx.x;     // hidden unit (lane)
    const int b   = blockIdx.x & 255;
    const int dir = blockIdx.x >> 8;
    const float* __restrict__ Whh = dir ? Whhb : Whhf;

    // W_hh rows i,f,g,o of unit k -> packed f16 pairs: 4 x 32 u32 = 128 VGPRs
    unsigned int wpI[32], wpF[32], wpG[32], wpO[32];
    #pragma unroll
    for (int j = 0; j < 32; ++j) {
        wpI[j] = pack2f16(Whh[(0 * Hsz + k) * Hsz + 2 * j], Whh[(0 * Hsz + k) * Hsz + 2 * j + 1]);
        wpF[j] = pack2f16(Whh[(1 * Hsz + k) * Hsz + 2 * j], Whh[(1 * Hsz + k) * Hsz + 2 * j + 1]);
        wpG[j] = pack2f16(Whh[(2 * Hsz + k) * Hsz + 2 * j], Whh[(2 * Hsz + k) * Hsz + 2 * j + 1]);
        wpO[j] = pack2f16(Whh[(3 * Hsz + k) * Hsz + 2 * j], Whh[(3 * Hsz + k) * Hsz + 2 * j + 1]);
    }

    const int* __restrict__ xrow = x + b * Ssz;
    const unsigned short* __restrict__ tb = tbl + (size_t)dir * Vpad * Gsz;

    // prologue: pg for steps 0,1 in regs; tids for steps 2,3 ready
    int tidA = xrow[dir ? Ssz - 3 : 2];
    int tidB = xrow[dir ? Ssz - 4 : 3];
    uint2 pgA = *(const uint2*)(tb + (size_t)xrow[dir ? Ssz - 1 : 0] * Gsz + 4 * k);
    uint2 pgB = *(const uint2*)(tb + (size_t)xrow[dir ? Ssz - 2 : 1] * Gsz + 4 * k);

    float c_ = 0.f, h_k = 0.f;
    int hpacked = 0;   // (h_{2j} f16 | h_{2j+1} f16 << 16) valid on even lanes

    #define LSTM_STEP(PG, TID, SOFF)                                          \
    {                                                                         \
        uint2 pg_new = *(const uint2*)(tb + (size_t)(TID) * Gsz + 4 * k);     \
        int spf = s + (SOFF); spf = spf < Ssz - 1 ? spf : Ssz - 1;            \
        int tid_new = xrow[dir ? Ssz - 1 - spf : spf];                        \
        h2 p01 = __builtin_bit_cast(h2, PG.x);                                \
        h2 p23 = __builtin_bit_cast(h2, PG.y);                                \
        float Ai = (float)p01.x, Af = (float)p01.y;                           \
        float Ag = (float)p23.x, Ao = (float)p23.y;                           \
        _Pragma("unroll")                                                     \
        for (int j = 0; j < 32; ++j) {                                        \
            h2 hv = __builtin_bit_cast(h2, __builtin_amdgcn_readlane(hpacked, 2 * j)); \
            Ai = __builtin_amdgcn_fdot2(hv, __builtin_bit_cast(h2, wpI[j]), Ai, false); \
            Af = __builtin_amdgcn_fdot2(hv, __builtin_bit_cast(h2, wpF[j]), Af, false); \
            Ag = __builtin_amdgcn_fdot2(hv, __builtin_bit_cast(h2, wpG[j]), Ag, false); \
            Ao = __builtin_amdgcn_fdot2(hv, __builtin_bit_cast(h2, wpO[j]), Ao, false); \
        }                                                                     \
        float gi = sigf(Ai), gf = sigf(Af), gG = tanhfast(Ag), go = sigf(Ao); \
        c_  = fmaf(gf, c_, gi * gG);                                          \
        h_k = go * tanhfast(c_);                                              \
        unsigned int hw = (unsigned int)f2h(h_k);                             \
        unsigned int nb_ = (unsigned int)__shfl_xor((int)hw, 1);              \
        hpacked = (int)((hw & 0xffffu) | (nb_ << 16));                        \
        PG = pg_new; TID = tid_new;                                           \
    }

    for (int s = 0; s < Ssz; s += 2) {
        LSTM_STEP(pgA, tidA, 4);   // step s:   pg(s+2) via tidA, tid(s+4)
        LSTM_STEP(pgB, tidB, 5);   // step s+1: pg(s+3) via tidB, tid(s+5)
    }
    #undef LSTM_STEP

    hfinal[((size_t)dir * Bsz + b) * Hsz + k] = h_k;
}

// ============================================================
// Kernel 3: out[b] = sigmoid([h_f, h_b] . fc_w + fc_b)
// ============================================================
__global__ void fc_head(const float* __restrict__ hf,
                        const float* __restrict__ fcw, const float* __restrict__ fcb,
                        float* __restrict__ out)
{
    const int b = threadIdx.x;
    float sum = fcb[0];
    const float* h1 = hf + b * Hsz;
    const float* h2_ = hf + Bsz * Hsz + b * Hsz;
    #pragma unroll 8
    for (int j = 0; j < Hsz; ++j) sum = fmaf(h1[j], fcw[j], sum);
    #pragma unroll 8
    for (int j = 0; j < Hsz; ++j) sum = fmaf(h2_[j], fcw[Hsz + j], sum);
    out[b] = 1.0f / (1.0f + __expf(-sum));
}

extern "C" void kernel_launch(void* const* d_in, const int* in_sizes, int n_in,
                              void* d_out, int out_size, void* d_ws, size_t ws_size,
                              hipStream_t stream)
{
    const int*   x    = (const int*)d_in[0];
    const float* emb  = (const float*)d_in[1];
    const float* Wihf = (const float*)d_in[2];
    const float* Whhf = (const float*)d_in[3];
    const float* bihf = (const float*)d_in[4];
    const float* bhhf = (const float*)d_in[5];
    const float* Wihb = (const float*)d_in[6];
    const float* Whhb = (const float*)d_in[7];
    const float* bihb = (const float*)d_in[8];
    const float* bhhb = (const float*)d_in[9];
    const float* fcw  = (const float*)d_in[10];
    const float* fcb  = (const float*)d_in[11];

    // ws layout (bytes):
    //   [0,        51249152)   tbl   2 x 50048 x 256 f16 (unit-major, bias folded)
    //   [51249152, 51380224)   hf    2*B*H f32
    //   [51380224, 64180224)   embp  50000*128 bf16 (padded)
    //   [64180224, 64311296)   Wp    2*256*128 bf16 (padded)
    unsigned short* tbl  = (unsigned short*)d_ws;
    float*          hf   = (float*)((char*)d_ws + 51249152u);
    unsigned short* embp = (unsigned short*)((char*)d_ws + 51380224u);
    unsigned short* Wp   = (unsigned short*)((char*)d_ws + 64180224u);

    conv_emb<<<25000, 256, 0, stream>>>(emb, embp);
    conv_w<<<256, 256, 0, stream>>>(Wihf, Wihb, Wp);
    pregate_mfma<<<dim3(391, 2, 2), 512, 0, stream>>>(embp, Wp,
                                                      bihf, bhhf, bihb, bhhb, tbl);
    lstm_rec<<<512, 64, 0, stream>>>(x, tbl, Whhf, Whhb, hf);
    fc_head<<<1, 256, 0, stream>>>(hf, fcw, fcb, (float*)d_out);
}